// Round 10
// baseline (224.807 us; speedup 1.0000x reference)
//
#include <hip/hip_runtime.h>

// ConvTranspose4d: temporal valid conv (KT=3) of ConvTranspose3d(stride 2, pad 1, k=3).
// out[co,f,od,oh,ow] = sum_{i,ci,kd,kh,kw} x[ci,f+i,id,ih,iw] * W[ci,co,i,kd,kh,kw]
// R10: co moved into LANES (block = 8co x 24 ow-groups); weights pre-packed to d_ws as
//   [class][ci][co][tap][3] (16B-padded) and loaded per-ci into VGPRs via VECTOR loads
//   -> ZERO inner-loop s_loads/lgkmcnt. Theory: per-CU scalar unit (~37K s_loads + SALU
//   ~ 50-60% of the cycle budget, shared by all 4 SIMDs) is the invisible wall that made
//   R8 (2x waves) and R6 (re-layout, same s_load count) neutral. Each thread: 1 co,
//   4 ow, 8 oh rows (weights reused across rows from regs). Makespan model (R9): all
//   blocks resident at t0; kernel time = heavy-class block duration -> attack per-wave
//   critical path, keep per-block work constant.

typedef float f4u __attribute__((ext_vector_type(4), aligned(4)));  // unaligned-ok vec4
typedef float f4a __attribute__((ext_vector_type(4)));              // 16B-aligned
typedef float f2a __attribute__((ext_vector_type(2)));              // 8B-aligned

namespace {
constexpr int T_ = 8, D_ = 24, H_ = 48, W_ = 48;
constexpr int TO = 6, DO_ = 47, HO = 95, WO = 95;
constexpr int XCS = T_ * D_ * H_ * W_;
constexpr int XFS = D_ * H_ * W_;
constexpr int XDS = H_ * W_;
constexpr long OCS = (long)TO * DO_ * HO * WO;
constexpr int OFS = DO_ * HO * WO;
constexpr int ODS = HO * WO;

// classes: S0 = od odd & oh odd (12 taps), S1 = od odd & oh even (6),
//          S2 = od even & oh odd (6), S3 = od even & oh even (3)
constexpr int S0_END = 828, S1_END = 1656, S2_END = 2520, NWG = 3384;
// packed weights: base + (ci*8+co)*WSTR + tap*3 + kw ; WSTR padded to multiple of 4
constexpr int PB0 = 0;
constexpr int PB1 = PB0 + 64 * 36;   // 2304
constexpr int PB2 = PB1 + 64 * 20;   // 3584
constexpr int PB3 = PB2 + 64 * 20;   // 4864 ; total 5632 floats = 22.5 KB in d_ws

__global__ __launch_bounds__(256) void pack_kernel(const float* __restrict__ w,
                                                   float* __restrict__ p) {
  const int tid = blockIdx.x * 256 + threadIdx.x;
  const int nthr = gridDim.x * 256;
  const int NDs[4] = {2, 2, 1, 1}, NHs[4] = {2, 1, 2, 1};
  const int WS[4] = {36, 20, 20, 12}, BS[4] = {PB0, PB1, PB2, PB3};
  for (int c = 0; c < 4; ++c) {
    const int ND = NDs[c], NH = NHs[c], NT = 3 * ND * NH;
    const int cnt = 64 * NT * 3;
    for (int e = tid; e < cnt; e += nthr) {
      const int kw = e % 3, tap = (e / 3) % NT;
      const int co = (e / (3 * NT)) % 8, ci = e / (3 * NT * 8);
      const int i_ = tap / (ND * NH), r2 = tap % (ND * NH);
      const int a = r2 / NH, b = r2 % NH;
      const int KD = (ND == 1) ? 1 : (a ? 2 : 0);
      const int KH = (NH == 1) ? 1 : (b ? 2 : 0);
      p[BS[c] + (ci * 8 + co) * WS[c] + tap * 3 + kw] =
          w[ci * 648 + co * 81 + i_ * 27 + KD * 9 + KH * 3 + kw];
    }
  }
}

template<int ND, int NH, int WSTR, int PBASE, int NROW>
__device__ __forceinline__ void body(
    const float* __restrict__ x, const float* __restrict__ wp,
    float* __restrict__ out, int f, int od, int ohb, int co, int t)
{
  constexpr int PH = (NH == 2) ? 1 : 0;        // oh parity of this class
  const int iwb = 2 * t;                       // thread owns ow = 4t..4t+3
  const int xext = (t < 23) ? 2 : 0;           // clamp: feeds only discarded ow=95
  const int id0 = (ND == 1) ? (od >> 1) : ((od + 1) >> 1);
  const int id1 = (od - 1) >> 1;               // used only when ND==2 (od>=1 then)
  const int rb0 = ohb * 8;                     // first row index (oh = 2*row+PH)

  float acc[NROW][4];
  #pragma unroll
  for (int r = 0; r < NROW; ++r) {
    acc[r][0] = 0.f; acc[r][1] = 0.f; acc[r][2] = 0.f; acc[r][3] = 0.f;
  }

  #pragma unroll 1
  for (int ci = 0; ci < 8; ++ci) {
    // per-(ci,co) weight block -> VGPRs via vector loads (per-lane address: co varies)
    float wr[WSTR];
    const float* pwv = wp + PBASE + (ci * 8 + co) * WSTR;
    #pragma unroll
    for (int q = 0; q < WSTR / 4; ++q)
      *(f4a*)(wr + 4 * q) = *(const f4a*)(pwv + 4 * q);

    const float* pxc = x + ci * XCS + iwb;
    #pragma unroll
    for (int i = 0; i < 3; ++i) {
      #pragma unroll
      for (int a = 0; a < ND; ++a) {
        #pragma unroll
        for (int b = 0; b < NH; ++b) {
          const int TAP = (i * ND + a) * NH + b;         // constant after unroll
          const float w0 = wr[TAP * 3 + 0];
          const float w1 = wr[TAP * 3 + 1];
          const float w2 = wr[TAP * 3 + 2];
          // ih for row r: PH==0 -> rb0+r (kh=1); PH==1: b==0 (kh=0) -> rb0+r+1,
          //               b==1 (kh=2) -> rb0+r
          const int ih_r0 = rb0 + ((PH == 1 && b == 0) ? 1 : 0);
          const float* pxb = pxc + (f + i) * XFS + (a ? id1 : id0) * XDS + ih_r0 * W_;
          #pragma unroll
          for (int r = 0; r < NROW; ++r) {               // rows reuse weight regs
            const float* px = pxb + r * W_;              // row offsets fold to immediates
            const f2a xa = *(const f2a*)px;              // iw = 2t, 2t+1
            const float xb = px[xext];                   // iw = 2t+2
            acc[r][0] = fmaf(xa.x, w1, acc[r][0]);                     // ow=4t   (kw=1)
            acc[r][2] = fmaf(xa.y, w1, acc[r][2]);                     // ow=4t+2 (kw=1)
            acc[r][1] = fmaf(xa.y, w0, fmaf(xa.x, w2, acc[r][1]));     // ow=4t+1
            acc[r][3] = fmaf(xb,   w0, fmaf(xa.y, w2, acc[r][3]));     // ow=4t+3
          }
        }
      }
    }
  }

  const long obase = (long)co * OCS + (long)f * OFS + (long)od * ODS + 4 * t;
  #pragma unroll
  for (int r = 0; r < NROW; ++r) {
    const int oh = 2 * (rb0 + r) + PH;
    float* po = out + obase + (long)oh * HO;
    if (t < 23) {
      f4u v; v.x = acc[r][0]; v.y = acc[r][1]; v.z = acc[r][2]; v.w = acc[r][3];
      *(f4u*)po = v;
    } else {                                   // ow = 92..94 (ow=95 doesn't exist)
      po[0] = acc[r][0]; po[1] = acc[r][1]; po[2] = acc[r][2];
    }
  }
}

__global__ __launch_bounds__(192) void convt4d_kernel(
    const float* __restrict__ x, const float* __restrict__ wp,
    float* __restrict__ out)
{
  const int tid = threadIdx.x;
  const int t = tid % 24;                      // ow group: ow in [4t, 4t+4)
  const int co = tid / 24;                     // one output channel per thread
  const int bid = blockIdx.x;
  if (bid < S0_END) {                          // od odd, oh odd (heavy class first)
    const int ohb = bid % 6, dd = (bid / 6) % 23, f = bid / 138;
    if (ohb < 5) body<2, 2, 36, PB0, 8>(x, wp, out, f, 2 * dd + 1, ohb, co, t);
    else         body<2, 2, 36, PB0, 7>(x, wp, out, f, 2 * dd + 1, ohb, co, t);
  } else if (bid < S1_END) {                   // od odd, oh even (48 rows = 6x8 exact)
    const int b2 = bid - S0_END;
    const int ohb = b2 % 6, dd = (b2 / 6) % 23, f = b2 / 138;
    body<2, 1, 20, PB1, 8>(x, wp, out, f, 2 * dd + 1, ohb, co, t);
  } else if (bid < S2_END) {                   // od even, oh odd
    const int b2 = bid - S1_END;
    const int ohb = b2 % 6, dd = (b2 / 6) % 24, f = b2 / 144;
    if (ohb < 5) body<1, 2, 20, PB2, 8>(x, wp, out, f, 2 * dd, ohb, co, t);
    else         body<1, 2, 20, PB2, 7>(x, wp, out, f, 2 * dd, ohb, co, t);
  } else {                                     // od even, oh even
    const int b2 = bid - S2_END;
    const int ohb = b2 % 6, dd = (b2 / 6) % 24, f = b2 / 144;
    body<1, 1, 12, PB3, 8>(x, wp, out, f, 2 * dd, ohb, co, t);
  }
}
}  // namespace

extern "C" void kernel_launch(void* const* d_in, const int* in_sizes, int n_in,
                              void* d_out, int out_size, void* d_ws, size_t ws_size,
                              hipStream_t stream) {
  const float* x = (const float*)d_in[0];
  const float* w = (const float*)d_in[1];
  float* out = (float*)d_out;
  float* wp = (float*)d_ws;                    // 5632 floats = 22.5 KB scratch
  hipLaunchKernelGGL(pack_kernel, dim3(6), dim3(256), 0, stream, w, wp);
  hipLaunchKernelGGL(convt4d_kernel, dim3(NWG), dim3(192), 0, stream, x, wp, out);
}

// Round 11
// 63.684 us; speedup vs baseline: 3.5300x; 3.5300x over previous
//
#include <hip/hip_runtime.h>

// ConvTranspose4d via bf16 MFMA (R11).
// Gather form: out[co,f,od,oh,ow] = sum_{ci,i,kd,kh,kw} x[ci,f+i,id,ih,iw]*W[ci,co,i,kd,kh,kw]
//   id=(od+1-kd)/2 parity-valid; kd in {0,2} (od odd, a=0/1) or {1} (od even); same for kh.
//   kw: ow even -> {1}; ow odd -> {0,2}. iw pair (n, n+1) with n=(ow-1)>>1 covers all kw.
// GEMM per class (pd,ph): M=16 (co 0..7 + zero pad), K = 8ci*3i*ND*NH*2c (c = iw slot),
//   N = 16 cols of one ow parity. One wave: (f,od,oh, 32-ow block) = even tile + odd tile
//   sharing B loads (x[n], x[n+1]); A differs per parity (c-slot weights / zeros).
// k = (((ci*3+i)*ND+a)*NH+b)*2+c ; per-8 k-group g: lane quarter q=l>>4, step s: g=s*4+q.
// A[l&15][k0+j] from packed table in d_ws; B[k0+j][l&15] built from 8 dword x loads +
// v_perm bf16-truncate packs. C/D: col=l&15, row=(l>>4)*4+reg (m89). Stores: (even,odd)
// adjacent -> 8B/lane, wave covers full 64B lines (no partial-line RMW; R5 lesson).
// Vector path (R4/R8, 73us) retired: stuck at 3.5x issue floor, no single pipe saturated.

typedef float  f32x4  __attribute__((ext_vector_type(4)));
typedef short  bf16x8 __attribute__((ext_vector_type(8)));   // 8 bf16 (guide Sec.3)
typedef unsigned int u32;
typedef u32    u32x4  __attribute__((ext_vector_type(4)));
typedef float  f2u    __attribute__((ext_vector_type(2), aligned(4)));

namespace {
constexpr int T_ = 8, D_ = 24, H_ = 48, W_ = 48;
constexpr int TO = 6, DO_ = 47, HO = 95, WO = 95;
constexpr int XCS = T_ * D_ * H_ * W_;
constexpr int XFS = D_ * H_ * W_;
constexpr int XDS = H_ * W_;
constexpr long OCS = (long)TO * DO_ * HO * WO;
constexpr int OFS = DO_ * HO * WO;
constexpr int ODS = HO * WO;

// classes: 0:(ND2,NH2) 1:(2,1) 2:(1,2) 3:(1,1); groups = K_pad/8
constexpr int AG[4] = {24, 12, 12, 8};
// short-offsets for (class*2 + pw); each (c,pw) block = AG[c]*128 shorts
constexpr int AOFFC[8] = {0, 3072, 6144, 7680, 9216, 10752, 12288, 13312};  // end 14336

__global__ __launch_bounds__(256) void pack_kernel(const float* __restrict__ w,
                                                   unsigned short* __restrict__ A) {
  const int tid = blockIdx.x * 256 + threadIdx.x;
  const int nthr = gridDim.x * 256;
  const int NDs[4] = {2, 2, 1, 1}, NHs[4] = {2, 1, 2, 1}, KR[4] = {192, 96, 96, 48};
  for (int c = 0; c < 4; ++c) {
    for (int pw = 0; pw < 2; ++pw) {
      const int cnt = AG[c] * 128;
      for (int e = tid; e < cnt; e += nthr) {
        const int j = e & 7, r = (e >> 3) & 15, g = e >> 7;
        const int k = g * 8 + j;
        float v = 0.f;
        if (r < 8 && k < KR[c]) {
          int gg, a = 0, b = 0, cc;
          if (c == 0)      { gg = g;               a = (j >> 2) & 1; b = (j >> 1) & 1; cc = j & 1; }
          else if (c == 1) { gg = 2 * g + (j >> 2); a = (j >> 1) & 1;                  cc = j & 1; }
          else if (c == 2) { gg = 2 * g + (j >> 2); b = (j >> 1) & 1;                  cc = j & 1; }
          else             { gg = 4 * g + (j >> 1);                                    cc = j & 1; }
          if (gg < 24) {
            const int ci = gg / 3, i = gg - 3 * (gg / 3);
            const int kd = (NDs[c] == 2) ? (a ? 2 : 0) : 1;
            const int kh = (NHs[c] == 2) ? (b ? 2 : 0) : 1;
            int kw = -1;
            if (cc == 0) kw = pw ? 0 : 1;
            else if (pw) kw = 2;                      // pw==0,c==1 -> zero slot
            if (kw >= 0) v = w[ci * 648 + r * 81 + i * 27 + kd * 9 + kh * 3 + kw];
          }
        }
        u32 u = __float_as_uint(v);
        u += 0x7FFFu + ((u >> 16) & 1u);              // RNE to bf16
        A[AOFFC[c * 2 + pw] + e] = (unsigned short)(u >> 16);
      }
    }
  }
}

template<int PD, int PH>
__device__ __forceinline__ void wave_body(
    const float* __restrict__ x, const unsigned short* __restrict__ A,
    float* __restrict__ out, int f, int od, int oh, int blk, int lane)
{
  constexpr int CLS = (PD && PH) ? 0 : PD ? 1 : PH ? 2 : 3;
  constexpr int NSTEP = (CLS == 0) ? 6 : (CLS == 3) ? 2 : 3;
  const int c15 = lane & 15, q = lane >> 4;
  const int n = blk * 16 + c15;                       // iw base; x[n], x[n+1] feed this col-pair
  const int id0 = PD ? ((od + 1) >> 1) : (od >> 1);
  const int ih0 = PH ? ((oh + 1) >> 1) : (oh >> 1);

  bf16x8 afe[NSTEP], afo[NSTEP];
  {
    const unsigned short* Ae = A + AOFFC[CLS * 2 + 0];
    const unsigned short* Ao = A + AOFFC[CLS * 2 + 1];
    #pragma unroll
    for (int s = 0; s < NSTEP; ++s) {
      const int g = s * 4 + q;
      afe[s] = *reinterpret_cast<const bf16x8*>(Ae + g * 128 + c15 * 8);
      afo[s] = *reinterpret_cast<const bf16x8*>(Ao + g * 128 + c15 * 8);
    }
  }
  f32x4 accE = {0.f, 0.f, 0.f, 0.f}, accO = {0.f, 0.f, 0.f, 0.f};
  const int pb = f * XFS + id0 * XDS + ih0 * W_ + n;
  const int hs = (n < 47) ? 1 : 0;                    // clamp last x[n+1] (masked/zero slots only)

  auto PAIR = [&](const float* p, u32& de, u32& dq) {
    const u32 bl = __float_as_uint(p[0]);             // x[n]
    const u32 bh = __float_as_uint(p[hs]);            // x[n+1]
    de = __builtin_amdgcn_perm(bh, bl, 0x07060302u);  // lo16=bf(x[n]) c0:kw1, hi16=bf(x[n+1]) c1:zeroA
    dq = __builtin_amdgcn_perm(bl, bh, 0x07060302u);  // lo16=bf(x[n+1]) c0:kw0, hi16=bf(x[n]) c1:kw2
  };

  #pragma unroll
  for (int s = 0; s < NSTEP; ++s) {
    const int G = s * 4 + q;
    u32 dE[4], dO[4];
    if constexpr (CLS == 0) {                         // 8-group = one (ci,i); j=(a,b,c)
      const int ci = G / 3, i = G - 3 * (G / 3);
      const float* p0 = x + pb + ci * XCS + i * XFS;
      PAIR(p0,            dE[0], dO[0]);
      PAIR(p0 - W_,       dE[1], dO[1]);
      PAIR(p0 - XDS,      dE[2], dO[2]);
      PAIR(p0 - XDS - W_, dE[3], dO[3]);
    } else if constexpr (CLS == 1) {                  // j=(gpar,a,c)
      const int g0 = 2 * G, g1 = 2 * G + 1;
      const int c0 = g0 / 3, i0 = g0 - 3 * (g0 / 3);
      const int c1 = g1 / 3, i1 = g1 - 3 * (g1 / 3);
      const float* p0 = x + pb + c0 * XCS + i0 * XFS;
      const float* p1 = x + pb + c1 * XCS + i1 * XFS;
      PAIR(p0,       dE[0], dO[0]);
      PAIR(p0 - XDS, dE[1], dO[1]);
      PAIR(p1,       dE[2], dO[2]);
      PAIR(p1 - XDS, dE[3], dO[3]);
    } else if constexpr (CLS == 2) {                  // j=(gpar,b,c)
      const int g0 = 2 * G, g1 = 2 * G + 1;
      const int c0 = g0 / 3, i0 = g0 - 3 * (g0 / 3);
      const int c1 = g1 / 3, i1 = g1 - 3 * (g1 / 3);
      const float* p0 = x + pb + c0 * XCS + i0 * XFS;
      const float* p1 = x + pb + c1 * XCS + i1 * XFS;
      PAIR(p0,      dE[0], dO[0]);
      PAIR(p0 - W_, dE[1], dO[1]);
      PAIR(p1,      dE[2], dO[2]);
      PAIR(p1 - W_, dE[3], dO[3]);
    } else {                                          // j=(g&3,c); pad k>=48 -> clamp, A=0
      #pragma unroll
      for (int d = 0; d < 4; ++d) {
        int gg = 4 * G + d; gg = (gg > 23) ? 23 : gg;
        const int ci = gg / 3, i = gg - 3 * (gg / 3);
        PAIR(x + pb + ci * XCS + i * XFS, dE[d], dO[d]);
      }
    }
    const u32x4 ue = {dE[0], dE[1], dE[2], dE[3]};
    const u32x4 uo = {dO[0], dO[1], dO[2], dO[3]};
    accE = __builtin_amdgcn_mfma_f32_16x16x32_bf16(afe[s], __builtin_bit_cast(bf16x8, ue), accE, 0, 0, 0);
    accO = __builtin_amdgcn_mfma_f32_16x16x32_bf16(afo[s], __builtin_bit_cast(bf16x8, uo), accO, 0, 0, 0);
  }

  if (lane < 32) {                                    // rows 0..7 = co; rows 8..15 discarded
    const long ob = (long)f * OFS + (long)od * ODS + (long)oh * HO + blk * 32 + 2 * c15;
    const bool full = !(blk == 2 && c15 == 15);       // ow=95 doesn't exist
    #pragma unroll
    for (int j = 0; j < 4; ++j) {
      float* po = out + (long)(q * 4 + j) * OCS + ob;
      if (full) { f2u v; v.x = accE[j]; v.y = accO[j]; *reinterpret_cast<f2u*>(po) = v; }
      else      { po[0] = accE[j]; }
    }
  }
}

constexpr int NWAVES = 6 * 47 * 95 * 3;               // 80370
constexpr int NBLK = (NWAVES + 3) / 4;                // 20093

__global__ __launch_bounds__(256) void convt4d_kernel(
    const float* __restrict__ x, const unsigned short* __restrict__ A,
    float* __restrict__ out)
{
  const int wid = blockIdx.x * 4 + (threadIdx.x >> 6);
  if (wid >= NWAVES) return;
  const int lane = threadIdx.x & 63;
  const int blk = wid % 3;
  int rest = wid / 3;
  const int oh = rest % 95; rest /= 95;
  const int od = rest % 47; const int f = rest / 47;
  if (od & 1) {
    if (oh & 1) wave_body<1, 1>(x, A, out, f, od, oh, blk, lane);
    else        wave_body<1, 0>(x, A, out, f, od, oh, blk, lane);
  } else {
    if (oh & 1) wave_body<0, 1>(x, A, out, f, od, oh, blk, lane);
    else        wave_body<0, 0>(x, A, out, f, od, oh, blk, lane);
  }
}
}  // namespace

extern "C" void kernel_launch(void* const* d_in, const int* in_sizes, int n_in,
                              void* d_out, int out_size, void* d_ws, size_t ws_size,
                              hipStream_t stream) {
  const float* x = (const float*)d_in[0];
  const float* w = (const float*)d_in[1];
  float* out = (float*)d_out;
  unsigned short* A = (unsigned short*)d_ws;          // 14336 shorts = 28 KB
  hipLaunchKernelGGL(pack_kernel, dim3(8), dim3(256), 0, stream, w, A);
  hipLaunchKernelGGL(convt4d_kernel, dim3(NBLK), dim3(256), 0, stream, x, A, out);
}